// Round 1
// baseline (284.576 us; speedup 1.0000x reference)
//
#include <hip/hip_runtime.h>
#include <hip/hip_bf16.h>

// Problem constants
#define B_   32
#define C_   128
#define H_   56
#define W_   56
#define KSEL 2
#define E_   8
#define KN_  128
// KS=3, PAD=1

typedef __attribute__((ext_vector_type(8))) short short8;   // 8 x bf16
typedef __attribute__((ext_vector_type(4))) float f32x4;    // MFMA accumulator

static __device__ __forceinline__ ushort f2bf(float f) {
  union { float f; uint u; } v; v.f = f;
  uint u = v.u;
  return (ushort)((u + 0x7fffu + ((u >> 16) & 1u)) >> 16);  // RNE
}

// ---------------------------------------------------------------------------
// Kernel 0: x fp32 NCHW -> bf16 NHWC with zero halo baked in.
//   xh[b][h'][w'][c], h',w' in [0,58); h=h'-1, w=w'-1; border cells zero.
// grid = (58, 32) blocks x 256 threads. Transpose via LDS.  (unchanged)
// ---------------------------------------------------------------------------
__global__ __launch_bounds__(256) void prep_x_kernel(
    const float* __restrict__ x, ushort* __restrict__ xh) {
  const int hp = blockIdx.x;   // 0..57
  const int b  = blockIdx.y;
  const int tid = threadIdx.x;
  ushort* rowp = xh + (size_t)(b * 58 + hp) * 58 * 128;

  if (hp == 0 || hp == 57) {            // zero halo rows
    uint4 z = make_uint4(0, 0, 0, 0);
    for (int l = tid; l < 464; l += 256) ((uint4*)rowp)[l] = z;
    return;
  }
  const int h = hp - 1;
  __shared__ __align__(16) ushort sT[56 * 136];   // [w][c], c-stride padded

  const float* xb = x + (size_t)b * C_ * H_ * W_ + h * W_;
#pragma unroll
  for (int it = 0; it < 7; ++it) {
    int i4 = tid + it * 256;            // 0..1791
    int c  = i4 / 14;
    int w4 = (i4 - c * 14) * 4;
    float4 v = *(const float4*)(xb + (size_t)c * (H_ * W_) + w4);
    sT[(w4 + 0) * 136 + c] = f2bf(v.x);
    sT[(w4 + 1) * 136 + c] = f2bf(v.y);
    sT[(w4 + 2) * 136 + c] = f2bf(v.z);
    sT[(w4 + 3) * 136 + c] = f2bf(v.w);
  }
  __syncthreads();
  for (int l = tid; l < 896; l += 256) {   // cells w'=1..56
    int w = l >> 4, sub = l & 15;
    uint4 v = *(const uint4*)&sT[w * 136 + sub * 8];
    *(uint4*)(rowp + (size_t)(w + 1) * 128 + sub * 8) = v;
  }
  if (tid < 32) {                           // halo cells w'=0,57
    int wp = (tid < 16) ? 0 : 57;
    uint4 z = make_uint4(0, 0, 0, 0);
    *(uint4*)(rowp + (size_t)wp * 128 + (tid & 15) * 8) = z;
  }
}

// ---------------------------------------------------------------------------
// Kernel 1: fuse 1x1 mix into 3x3 weights (fp32 tiled GEMM), emit bf16 in
// MFMA B-fragment-tiled layout:
//   Weff2[e][j][nt(8)][ct(4)][lane(64)][8]  (ushort)
//   lane l of tile (nt,ct): o = nt*16 + (l&15), c = ct*32 + (l>>4)*8 .. +7
// => one tile = 1 KB contiguous = one fully-coalesced wave dwordx4 load.
// Weff2[e][j][o][c] = sum_k Wch[e][o][C_+k] * Ws[e][k][c][j]; +Wch[e][o][c] @ j=4
// grid = (8 e, 4 o-tiles, 4 c-tiles) x 256 threads.
// ---------------------------------------------------------------------------
__global__ __launch_bounds__(256) void fuse_weights_kernel(
    const float* __restrict__ Ws,    // [E][KN][C][9]
    const float* __restrict__ Wch,   // [E][C][256]
    ushort* __restrict__ Weff) {     // tiled bf16, see above
  const int e  = blockIdx.x;
  const int o0 = blockIdx.y * 32;
  const int c0 = blockIdx.z * 32;
  const int tid = threadIdx.x;
  const int ol = tid >> 3;           // 0..31
  const int cq = (tid & 7) * 4;      // 0..28

  __shared__ __align__(16) float sA[32 * 129];       // Wch gate part [o][k]
  __shared__ __align__(16) float sB[32 * 32 * 12];   // Ws chunk [k][c][12]

  // stage sA (whole K=128): 32 o-rows x 32 float4 chunks (128 k each)
#pragma unroll
  for (int it = 0; it < 4; ++it) {
    int i4 = tid + it * 256;         // 0..1023
    int o  = i4 >> 5;                // 0..31
    int kk = (i4 & 31) * 4;          // 0..124
    float4 v = *(const float4*)(Wch + (size_t)(e * C_ + o0 + o) * 256 + 128 + kk);
    sA[o * 129 + kk + 0] = v.x;
    sA[o * 129 + kk + 1] = v.y;
    sA[o * 129 + kk + 2] = v.z;
    sA[o * 129 + kk + 3] = v.w;
  }

  float acc[9][4];
#pragma unroll
  for (int j = 0; j < 9; ++j)
#pragma unroll
    for (int c2 = 0; c2 < 4; ++c2) acc[j][c2] = 0.f;

  for (int k0 = 0; k0 < 128; k0 += 32) {
    __syncthreads();
    {  // stage sB: 32 k-rows, each 288 contiguous floats (32c x 9j), repack [k][c][12]
      int k = tid >> 3, seg = tid & 7;
      const float* src = Ws + ((size_t)(e * KN_ + k0 + k) * C_ + c0) * 9 + seg * 36;
      float vb[36];
#pragma unroll
      for (int q = 0; q < 9; ++q) {
        float4 v = *(const float4*)(src + q * 4);
        vb[q * 4 + 0] = v.x; vb[q * 4 + 1] = v.y;
        vb[q * 4 + 2] = v.z; vb[q * 4 + 3] = v.w;
      }
      int c = seg * 4, j = 0;   // seg*36 = (seg*4)*9 exactly
#pragma unroll
      for (int m = 0; m < 36; ++m) {
        sB[(k * 32 + c) * 12 + j] = vb[m];
        if (++j == 9) { j = 0; ++c; }
      }
    }
    __syncthreads();
    for (int k = 0; k < 32; ++k) {
      float a = sA[ol * 129 + k0 + k];
#pragma unroll
      for (int c2 = 0; c2 < 4; ++c2) {
        const float* bp = &sB[(k * 32 + cq + c2) * 12];
#pragma unroll
        for (int j = 0; j < 9; ++j) acc[j][c2] += a * bp[j];
      }
    }
  }

  const int o = o0 + ol;
#pragma unroll
  for (int c2 = 0; c2 < 4; ++c2)
    acc[4][c2] += Wch[(size_t)(e * C_ + o) * 256 + c0 + cq + c2];

  // tiled store: nt = o>>4, ct = blockIdx.z, lane = (cq>>3)*16 + (o&15)
  const int nt   = (o0 >> 4) + (ol >> 4);
  const int lane = ((cq >> 3) << 4) | (ol & 15);
#pragma unroll
  for (int j = 0; j < 9; ++j) {
    uint lo = (uint)f2bf(acc[j][0]) | ((uint)f2bf(acc[j][1]) << 16);
    uint hi = (uint)f2bf(acc[j][2]) | ((uint)f2bf(acc[j][3]) << 16);
    size_t base = ((((size_t)(e * 9 + j) * 8 + nt) * 4 + blockIdx.z) * 64 + lane) * 8
                  + (cq & 4);
    *(uint2*)(Weff + base) = make_uint2(lo, hi);
  }
}

// ---------------------------------------------------------------------------
// Kernel 2: implicit-GEMM MFMA conv from bf16 NHWC-halo x.
// Block = (b,g) x 4 output rows: M=224 (14 m-tiles), N=128 (8 n-tiles), K=1152.
// 4 waves: wave (mh,nh) covers 7 m-tiles x 4 n-tiles; acc 7x4 f32x4.
// sX: [6 rows][58 cols][32c] bf16, cell stride padded to 40 ushorts (2-way banks).
// B fragments: loaded directly from L2-resident fragment-tiled Weff (no sW LDS,
// no per-dy restage barriers). Barriers: 2 per cc (8 total) vs 28 before.
// XCD-affinity swizzle: 4 consecutive b's per XCD -> xh working set 3.4MB < 4MB L2.
// ---------------------------------------------------------------------------
#define XSTR 40

__global__ __launch_bounds__(256, 3) void conv_mfma_kernel(
    const ushort* __restrict__ xh,   // [B][58][58][128] bf16
    const int* __restrict__ gate,    // [B][KSEL]
    const ushort* __restrict__ Weff, // fragment-tiled bf16 (see fuse kernel)
    float* __restrict__ out) {       // [B][KSEL][C][H][W] fp32
  // --- swizzled block mapping: XCD = P%8 gets b in [4*xcd, 4*xcd+4) ---
  const int P   = blockIdx.x;        // 0..895, grid is 1-D
  const int xcd = P & 7;
  const int s   = P >> 3;            // 0..111
  const int bl  = s / 28;            // 0..3
  const int r1  = s - bl * 28;
  const int g   = r1 / 14;           // 0..1
  const int ht  = r1 - g * 14;       // 0..13
  const int b   = xcd * 4 + bl;
  const int bg  = b * 2 + g;
  const int h0  = ht * 4;
  const int e   = gate[bg];

  const int tid = threadIdx.x;
  const int wv = tid >> 6, lane = tid & 63;
  const int l15 = lane & 15, kq = lane >> 4;
  const int mh = wv >> 1, nh = wv & 1;

  __shared__ __align__(16) ushort sX[6 * 58 * XSTR];   // 27840 B

  f32x4 acc[7][4];
#pragma unroll
  for (int t = 0; t < 7; ++t)
#pragma unroll
    for (int i = 0; i < 4; ++i) acc[t][i] = (f32x4){0.f, 0.f, 0.f, 0.f};

  int addr0[7];
#pragma unroll
  for (int t = 0; t < 7; ++t) {
    int p = mh * 112 + t * 16 + l15;   // 0..223
    int r = p / 56;
    int w = p - r * 56;
    addr0[t] = (r * 58 + w) * XSTR + kq * 8;
  }

  const ushort* xb = xh + (size_t)b * 58 * 58 * 128;
  // per-lane fragment base: e, nh, lane folded in; j/cc/i are literal offsets
  //   offset(e,j,nt,ct,lane) = ((((e*9+j)*8+nt)*4+ct)*64+lane)*8 ushorts
  const ushort* wlane = Weff + (size_t)e * (9 * 8 * 4 * 64 * 8)
                             + (size_t)(nh * 4) * (4 * 64 * 8)
                             + (size_t)lane * 8;

  for (int cc = 0; cc < 4; ++cc) {
    const int c0 = cc * 32;
    __syncthreads();   // previous cc's sX reads complete
    // stage sX: 6 rows x 58 cols x 4 sub-chunks of 16 B
    for (int l = tid; l < 1392; l += 256) {
      int row = l / 232;
      int rem = l - row * 232;
      int col = rem >> 2, sub = rem & 3;
      uint4 v = *(const uint4*)(xb + ((size_t)(h0 + row) * 58 + col) * 128 + c0 + sub * 8);
      *(uint4*)&sX[(row * 58 + col) * XSTR + sub * 8] = v;
    }
    __syncthreads();   // sX visible
#pragma unroll
    for (int dy = 0; dy < 3; ++dy) {
#pragma unroll
      for (int dx = 0; dx < 3; ++dx) {
        const int j = dy * 3 + dx;
        short8 bfr[4];
#pragma unroll
        for (int i = 0; i < 4; ++i)
          bfr[i] = *(const short8*)(wlane + (size_t)j * (8 * 4 * 64 * 8)
                                          + (size_t)i * (4 * 64 * 8)
                                          + (size_t)cc * (64 * 8));
        const int ao = (dy * 58 + dx) * XSTR;
#pragma unroll
        for (int t = 0; t < 7; ++t) {
          short8 a = *(const short8*)&sX[addr0[t] + ao];
#pragma unroll
          for (int i = 0; i < 4; ++i)
            acc[t][i] = __builtin_amdgcn_mfma_f32_16x16x32_bf16(a, bfr[i], acc[t][i], 0, 0, 0);
        }
      }
    }
  }

  // epilogue: lane rows p = mh*112 + t*16 + kq*4 + reg; col o = nh*64 + i*16 + l15
#pragma unroll
  for (int t = 0; t < 7; ++t) {
    int p0 = mh * 112 + t * 16 + kq * 4;
    int r  = p0 / 56;
    int w0 = p0 - r * 56;
    int h  = h0 + r;
#pragma unroll
    for (int i = 0; i < 4; ++i) {
      int o = nh * 64 + i * 16 + l15;
      float* op = out + (((size_t)bg * C_ + o) * H_ + h) * W_ + w0;
      *(float4*)op = make_float4(acc[t][i][0], acc[t][i][1], acc[t][i][2], acc[t][i][3]);
    }
  }
}

extern "C" void kernel_launch(void* const* d_in, const int* in_sizes, int n_in,
                              void* d_out, int out_size, void* d_ws, size_t ws_size,
                              hipStream_t stream) {
  const float* x    = (const float*)d_in[0];   // [32,128,56,56]
  const int*   gate = (const int*)d_in[1];     // [32,2]
  const float* Ws   = (const float*)d_in[2];   // [8,128,128,3,3]
  const float* Wch  = (const float*)d_in[3];   // [8,128,256,1,1]
  float* out = (float*)d_out;                  // [32,2,128,56,56]

  ushort* xh   = (ushort*)d_ws;                        // 32*58*58*128 bf16 = 27.56 MB
  ushort* Weff = xh + (size_t)32 * 58 * 58 * 128;      // [8][9][8][4][64][8] bf16 = 2.36 MB

  dim3 g0(58, 32);
  prep_x_kernel<<<g0, 256, 0, stream>>>(x, xh);

  dim3 g1(8, 4, 4);
  fuse_weights_kernel<<<g1, 256, 0, stream>>>(Ws, Wch, Weff);

  dim3 g2(896);
  conv_mfma_kernel<<<g2, 256, 0, stream>>>(xh, gate, Weff, out);
}

// Round 2
// 241.224 us; speedup vs baseline: 1.1797x; 1.1797x over previous
//
#include <hip/hip_runtime.h>
#include <hip/hip_bf16.h>

// Problem constants
#define B_   32
#define C_   128
#define H_   56
#define W_   56
#define KSEL 2
#define E_   8
#define KN_  128
// KS=3, PAD=1

typedef __attribute__((ext_vector_type(8))) short short8;   // 8 x bf16
typedef __attribute__((ext_vector_type(4))) float f32x4;    // MFMA accumulator

static __device__ __forceinline__ ushort f2bf(float f) {
  union { float f; uint u; } v; v.f = f;
  uint u = v.u;
  return (ushort)((u + 0x7fffu + ((u >> 16) & 1u)) >> 16);  // RNE
}

// ---------------------------------------------------------------------------
// Kernel 0: x fp32 NCHW -> bf16 NHWC with zero halo baked in.
//   xh[b][h'][w'][c], h',w' in [0,58); h=h'-1, w=w'-1; border cells zero.
// grid = (58, 32) blocks x 256 threads. Transpose via LDS.  (unchanged)
// ---------------------------------------------------------------------------
__global__ __launch_bounds__(256) void prep_x_kernel(
    const float* __restrict__ x, ushort* __restrict__ xh) {
  const int hp = blockIdx.x;   // 0..57
  const int b  = blockIdx.y;
  const int tid = threadIdx.x;
  ushort* rowp = xh + (size_t)(b * 58 + hp) * 58 * 128;

  if (hp == 0 || hp == 57) {            // zero halo rows
    uint4 z = make_uint4(0, 0, 0, 0);
    for (int l = tid; l < 464; l += 256) ((uint4*)rowp)[l] = z;
    return;
  }
  const int h = hp - 1;
  __shared__ __align__(16) ushort sT[56 * 136];   // [w][c], c-stride padded

  const float* xb = x + (size_t)b * C_ * H_ * W_ + h * W_;
#pragma unroll
  for (int it = 0; it < 7; ++it) {
    int i4 = tid + it * 256;            // 0..1791
    int c  = i4 / 14;
    int w4 = (i4 - c * 14) * 4;
    float4 v = *(const float4*)(xb + (size_t)c * (H_ * W_) + w4);
    sT[(w4 + 0) * 136 + c] = f2bf(v.x);
    sT[(w4 + 1) * 136 + c] = f2bf(v.y);
    sT[(w4 + 2) * 136 + c] = f2bf(v.z);
    sT[(w4 + 3) * 136 + c] = f2bf(v.w);
  }
  __syncthreads();
  for (int l = tid; l < 896; l += 256) {   // cells w'=1..56
    int w = l >> 4, sub = l & 15;
    uint4 v = *(const uint4*)&sT[w * 136 + sub * 8];
    *(uint4*)(rowp + (size_t)(w + 1) * 128 + sub * 8) = v;
  }
  if (tid < 32) {                           // halo cells w'=0,57
    int wp = (tid < 16) ? 0 : 57;
    uint4 z = make_uint4(0, 0, 0, 0);
    *(uint4*)(rowp + (size_t)wp * 128 + (tid & 15) * 8) = z;
  }
}

// ---------------------------------------------------------------------------
// Kernel 1: fuse 1x1 mix into 3x3 weights (fp32 tiled GEMM), emit bf16 in
// MFMA B-fragment-tiled layout:
//   Weff2[e][j][nt(8)][ct(4)][lane(64)][8]  (ushort)
//   lane l of tile (nt,ct): o = nt*16 + (l&15), c = ct*32 + (l>>4)*8 .. +7
// => one tile = 1 KB contiguous = one fully-coalesced wave dwordx4 load.
// Weff2[e][j][o][c] = sum_k Wch[e][o][C_+k] * Ws[e][k][c][j]; +Wch[e][o][c] @ j=4
// grid = (8 e, 4 o-tiles, 4 c-tiles) x 256 threads.  (unchanged)
// ---------------------------------------------------------------------------
__global__ __launch_bounds__(256) void fuse_weights_kernel(
    const float* __restrict__ Ws,    // [E][KN][C][9]
    const float* __restrict__ Wch,   // [E][C][256]
    ushort* __restrict__ Weff) {     // tiled bf16, see above
  const int e  = blockIdx.x;
  const int o0 = blockIdx.y * 32;
  const int c0 = blockIdx.z * 32;
  const int tid = threadIdx.x;
  const int ol = tid >> 3;           // 0..31
  const int cq = (tid & 7) * 4;      // 0..28

  __shared__ __align__(16) float sA[32 * 129];       // Wch gate part [o][k]
  __shared__ __align__(16) float sB[32 * 32 * 12];   // Ws chunk [k][c][12]

  // stage sA (whole K=128): 32 o-rows x 32 float4 chunks (128 k each)
#pragma unroll
  for (int it = 0; it < 4; ++it) {
    int i4 = tid + it * 256;         // 0..1023
    int o  = i4 >> 5;                // 0..31
    int kk = (i4 & 31) * 4;          // 0..124
    float4 v = *(const float4*)(Wch + (size_t)(e * C_ + o0 + o) * 256 + 128 + kk);
    sA[o * 129 + kk + 0] = v.x;
    sA[o * 129 + kk + 1] = v.y;
    sA[o * 129 + kk + 2] = v.z;
    sA[o * 129 + kk + 3] = v.w;
  }

  float acc[9][4];
#pragma unroll
  for (int j = 0; j < 9; ++j)
#pragma unroll
    for (int c2 = 0; c2 < 4; ++c2) acc[j][c2] = 0.f;

  for (int k0 = 0; k0 < 128; k0 += 32) {
    __syncthreads();
    {  // stage sB: 32 k-rows, each 288 contiguous floats (32c x 9j), repack [k][c][12]
      int k = tid >> 3, seg = tid & 7;
      const float* src = Ws + ((size_t)(e * KN_ + k0 + k) * C_ + c0) * 9 + seg * 36;
      float vb[36];
#pragma unroll
      for (int q = 0; q < 9; ++q) {
        float4 v = *(const float4*)(src + q * 4);
        vb[q * 4 + 0] = v.x; vb[q * 4 + 1] = v.y;
        vb[q * 4 + 2] = v.z; vb[q * 4 + 3] = v.w;
      }
      int c = seg * 4, j = 0;   // seg*36 = (seg*4)*9 exactly
#pragma unroll
      for (int m = 0; m < 36; ++m) {
        sB[(k * 32 + c) * 12 + j] = vb[m];
        if (++j == 9) { j = 0; ++c; }
      }
    }
    __syncthreads();
    for (int k = 0; k < 32; ++k) {
      float a = sA[ol * 129 + k0 + k];
#pragma unroll
      for (int c2 = 0; c2 < 4; ++c2) {
        const float* bp = &sB[(k * 32 + cq + c2) * 12];
#pragma unroll
        for (int j = 0; j < 9; ++j) acc[j][c2] += a * bp[j];
      }
    }
  }

  const int o = o0 + ol;
#pragma unroll
  for (int c2 = 0; c2 < 4; ++c2)
    acc[4][c2] += Wch[(size_t)(e * C_ + o) * 256 + c0 + cq + c2];

  // tiled store: nt = o>>4, ct = blockIdx.z, lane = (cq>>3)*16 + (o&15)
  const int nt   = (o0 >> 4) + (ol >> 4);
  const int lane = ((cq >> 3) << 4) | (ol & 15);
#pragma unroll
  for (int j = 0; j < 9; ++j) {
    uint lo = (uint)f2bf(acc[j][0]) | ((uint)f2bf(acc[j][1]) << 16);
    uint hi = (uint)f2bf(acc[j][2]) | ((uint)f2bf(acc[j][3]) << 16);
    size_t base = ((((size_t)(e * 9 + j) * 8 + nt) * 4 + blockIdx.z) * 64 + lane) * 8
                  + (cq & 4);
    *(uint2*)(Weff + base) = make_uint2(lo, hi);
  }
}

// ---------------------------------------------------------------------------
// Kernel 2: implicit-GEMM MFMA conv from bf16 NHWC-halo x.
// Block = (b,g) x 4 output rows: M=224 (14 m-tiles), N=128 (8 n-tiles), K=1152.
// 4 waves: wave (mh,nh) covers 7 m-tiles x 4 n-tiles; acc 7x4 f32x4.
// sX: [6 rows][58 cols][32c] bf16, cell stride padded to 40 ushorts.
// B fragments loaded directly from L2-resident fragment-tiled Weff (no sW LDS).
// NEW: LDS-transposed epilogue — per o the block's output slab is exactly
// 896 contiguous, 128B-aligned bytes (4 rows x 56 w; h0 mult of 4). Stage acc
// into LDS in 4 groups of 32 o, then all threads stream full-line float4
// writes. Eliminates partial-line write amplification + write-allocate reads.
// ---------------------------------------------------------------------------
#define XSTR 40
#define OSTR 228   // f32 epilogue o-stride (224 + 4 pad: breaks 32-bank alias)

__global__ __launch_bounds__(256, 3) void conv_mfma_kernel(
    const ushort* __restrict__ xh,   // [B][58][58][128] bf16
    const int* __restrict__ gate,    // [B][KSEL]
    const ushort* __restrict__ Weff, // fragment-tiled bf16 (see fuse kernel)
    float* __restrict__ out) {       // [B][KSEL][C][H][W] fp32
  // --- swizzled block mapping: XCD = P%8 gets b in [4*xcd, 4*xcd+4) ---
  const int P   = blockIdx.x;        // 0..895, grid is 1-D
  const int xcd = P & 7;
  const int s   = P >> 3;            // 0..111
  const int bl  = s / 28;            // 0..3
  const int r1  = s - bl * 28;
  const int g   = r1 / 14;           // 0..1
  const int ht  = r1 - g * 14;       // 0..13
  const int b   = xcd * 4 + bl;
  const int bg  = b * 2 + g;
  const int h0  = ht * 4;
  const int e   = gate[bg];

  const int tid = threadIdx.x;
  const int wv = tid >> 6, lane = tid & 63;
  const int l15 = lane & 15, kq = lane >> 4;
  const int mh = wv >> 1, nh = wv & 1;

  // union LDS: sX (bf16 staging, 27840 B) / sO (f32 epilogue, 29184 B)
  __shared__ __align__(16) char smem[32 * OSTR * 4];   // 29184 B
  ushort* sX = (ushort*)smem;
  float*  sO = (float*)smem;

  f32x4 acc[7][4];
#pragma unroll
  for (int t = 0; t < 7; ++t)
#pragma unroll
    for (int i = 0; i < 4; ++i) acc[t][i] = (f32x4){0.f, 0.f, 0.f, 0.f};

  int addr0[7];
#pragma unroll
  for (int t = 0; t < 7; ++t) {
    int p = mh * 112 + t * 16 + l15;   // 0..223
    int r = p / 56;
    int w = p - r * 56;
    addr0[t] = (r * 58 + w) * XSTR + kq * 8;
  }

  const ushort* xb = xh + (size_t)b * 58 * 58 * 128;
  // per-lane fragment base: e, nh, lane folded in; j/cc/i are literal offsets
  //   offset(e,j,nt,ct,lane) = ((((e*9+j)*8+nt)*4+ct)*64+lane)*8 ushorts
  const ushort* wlane = Weff + (size_t)e * (9 * 8 * 4 * 64 * 8)
                             + (size_t)(nh * 4) * (4 * 64 * 8)
                             + (size_t)lane * 8;

  for (int cc = 0; cc < 4; ++cc) {
    const int c0 = cc * 32;
    __syncthreads();   // previous cc's sX reads complete
    // stage sX: 6 rows x 58 cols x 4 sub-chunks of 16 B
    for (int l = tid; l < 1392; l += 256) {
      int row = l / 232;
      int rem = l - row * 232;
      int col = rem >> 2, sub = rem & 3;
      uint4 v = *(const uint4*)(xb + ((size_t)(h0 + row) * 58 + col) * 128 + c0 + sub * 8);
      *(uint4*)&sX[(row * 58 + col) * XSTR + sub * 8] = v;
    }
    __syncthreads();   // sX visible
#pragma unroll
    for (int dy = 0; dy < 3; ++dy) {
#pragma unroll
      for (int dx = 0; dx < 3; ++dx) {
        const int j = dy * 3 + dx;
        short8 bfr[4];
#pragma unroll
        for (int i = 0; i < 4; ++i)
          bfr[i] = *(const short8*)(wlane + (size_t)j * (8 * 4 * 64 * 8)
                                          + (size_t)i * (4 * 64 * 8)
                                          + (size_t)cc * (64 * 8));
        const int ao = (dy * 58 + dx) * XSTR;
#pragma unroll
        for (int t = 0; t < 7; ++t) {
          short8 a = *(const short8*)&sX[addr0[t] + ao];
#pragma unroll
          for (int i = 0; i < 4; ++i)
            acc[t][i] = __builtin_amdgcn_mfma_f32_16x16x32_bf16(a, bfr[i], acc[t][i], 0, 0, 0);
        }
      }
    }
  }

  // -------- LDS-transposed epilogue: 4 groups of 32 o --------
  // wave (mh,nh) owns rows p = mh*112 + t*16 + kq*4 + reg (r = p/56 in 0..3),
  // cols o = nh*64 + i*16 + l15. Group gq covers o in [32*gq, 32*gq+32):
  // staged by the two waves with nh == gq>>1, i in {(gq&1)*2, (gq&1)*2+1}.
  __syncthreads();   // all sX reads done before overwrite
  for (int gq = 0; gq < 4; ++gq) {
    if (nh == (gq >> 1)) {
      const int gg = gq & 1;
#pragma unroll
      for (int ii = 0; ii < 2; ++ii) {
        const int i = gg * 2 + ii;
#pragma unroll
        for (int t = 0; t < 7; ++t) {
          int p0 = mh * 112 + t * 16 + kq * 4;
          int r  = p0 / 56;
          int w0 = p0 - r * 56;
          *(float4*)&sO[(ii * 16 + l15) * OSTR + r * 56 + w0] =
              make_float4(acc[t][i][0], acc[t][i][1], acc[t][i][2], acc[t][i][3]);
        }
      }
    }
    __syncthreads();   // staged data visible
    // write out: 32 o x 56 float4 = 1792 pieces; per o: 896 contiguous bytes
    // = 7 full 128B lines (base line-aligned: o*12544 and h0*224 both %128==0)
    {
      float* ob = out + ((size_t)bg * C_ + 32 * gq) * (H_ * W_) + (size_t)h0 * W_;
#pragma unroll
      for (int k = 0; k < 7; ++k) {
        int idx = k * 256 + tid;        // 0..1791
        int ol  = idx / 56;
        int pos = idx - ol * 56;
        float4 v = *(const float4*)&sO[ol * OSTR + pos * 4];
        *(float4*)(ob + (size_t)ol * (H_ * W_) + pos * 4) = v;
      }
    }
    __syncthreads();   // write-out reads done before next group staging
  }
}

extern "C" void kernel_launch(void* const* d_in, const int* in_sizes, int n_in,
                              void* d_out, int out_size, void* d_ws, size_t ws_size,
                              hipStream_t stream) {
  const float* x    = (const float*)d_in[0];   // [32,128,56,56]
  const int*   gate = (const int*)d_in[1];     // [32,2]
  const float* Ws   = (const float*)d_in[2];   // [8,128,128,3,3]
  const float* Wch  = (const float*)d_in[3];   // [8,128,256,1,1]
  float* out = (float*)d_out;                  // [32,2,128,56,56]

  ushort* xh   = (ushort*)d_ws;                        // 32*58*58*128 bf16 = 27.56 MB
  ushort* Weff = xh + (size_t)32 * 58 * 58 * 128;      // [8][9][8][4][64][8] bf16 = 2.36 MB

  dim3 g0(58, 32);
  prep_x_kernel<<<g0, 256, 0, stream>>>(x, xh);

  dim3 g1(8, 4, 4);
  fuse_weights_kernel<<<g1, 256, 0, stream>>>(Ws, Wch, Weff);

  dim3 g2(896);
  conv_mfma_kernel<<<g2, 256, 0, stream>>>(xh, gate, Weff, out);
}

// Round 3
// 234.849 us; speedup vs baseline: 1.2117x; 1.0271x over previous
//
#include <hip/hip_runtime.h>
#include <hip/hip_bf16.h>

// Problem constants
#define B_   32
#define C_   128
#define H_   56
#define W_   56
#define KSEL 2
#define E_   8
#define KN_  128
// KS=3, PAD=1

typedef __attribute__((ext_vector_type(8))) short short8;   // 8 x bf16
typedef __attribute__((ext_vector_type(4))) float f32x4;    // MFMA accumulator

static __device__ __forceinline__ ushort f2bf(float f) {
  union { float f; uint u; } v; v.f = f;
  uint u = v.u;
  return (ushort)((u + 0x7fffu + ((u >> 16) & 1u)) >> 16);  // RNE
}

// xh layout (conv-ready LDS image): [b][cc(4)][hp(58)][cell(64)][40 ushorts]
//   cell w' holds c = cc*32 .. cc*32+31 in its first 32 ushorts, 8 pad.
//   cells 58..63 and all halo cells/rows are zero. Row = 5120 B.
#define CELL_US 40
#define ROW_US  2560          // 64 cells * 40
#define ROW_B   5120
#define REG_B   30720         // 6 rows staged per (cc, h0)

// ---------------------------------------------------------------------------
// Kernel 0: x fp32 NCHW -> bf16 padded-cc-plane layout with zero halo.
// grid = (58, 32) blocks x 256 threads. Transpose via LDS.
// ---------------------------------------------------------------------------
__global__ __launch_bounds__(256) void prep_x_kernel(
    const float* __restrict__ x, ushort* __restrict__ xh) {
  const int hp = blockIdx.x;   // 0..57
  const int b  = blockIdx.y;
  const int tid = threadIdx.x;

  if (hp == 0 || hp == 57) {            // zero halo rows (all 4 cc planes)
    uint4 z = make_uint4(0, 0, 0, 0);
#pragma unroll
    for (int cc = 0; cc < 4; ++cc) {
      ushort* rp = xh + ((size_t)(b * 4 + cc) * 58 + hp) * ROW_US;
      for (int l = tid; l < 320; l += 256) ((uint4*)rp)[l] = z;
    }
    return;
  }
  const int h = hp - 1;
  __shared__ __align__(16) ushort sT[56 * 136];   // [w][c], c-stride padded

  const float* xb = x + (size_t)b * C_ * H_ * W_ + h * W_;
#pragma unroll
  for (int it = 0; it < 7; ++it) {
    int i4 = tid + it * 256;            // 0..1791
    int c  = i4 / 14;
    int w4 = (i4 - c * 14) * 4;
    float4 v = *(const float4*)(xb + (size_t)c * (H_ * W_) + w4);
    sT[(w4 + 0) * 136 + c] = f2bf(v.x);
    sT[(w4 + 1) * 136 + c] = f2bf(v.y);
    sT[(w4 + 2) * 136 + c] = f2bf(v.z);
    sT[(w4 + 3) * 136 + c] = f2bf(v.w);
  }
  __syncthreads();
  // write 4 cc-plane rows: 4 * 64 cells * 5 uint4 = 1280 chunks, contiguous
  for (int q = tid; q < 1280; q += 256) {
    int cc  = q / 320, rem = q - cc * 320;
    int cell = rem / 5, sub = rem - cell * 5;
    uint4 v = make_uint4(0, 0, 0, 0);
    if (sub < 4 && cell >= 1 && cell <= 56)
      v = *(const uint4*)&sT[(cell - 1) * 136 + cc * 32 + sub * 8];
    ushort* rp = xh + ((size_t)(b * 4 + cc) * 58 + hp) * ROW_US;
    *(uint4*)(rp + cell * CELL_US + sub * 8) = v;
  }
}

// ---------------------------------------------------------------------------
// Kernel 1: fuse 1x1 mix into 3x3 weights (fp32 tiled GEMM), emit bf16 in
// MFMA B-fragment-tiled layout:
//   Weff2[e][j][nt(8)][ct(4)][lane(64)][8]  (ushort)  (unchanged)
// ---------------------------------------------------------------------------
__global__ __launch_bounds__(256) void fuse_weights_kernel(
    const float* __restrict__ Ws,    // [E][KN][C][9]
    const float* __restrict__ Wch,   // [E][C][256]
    ushort* __restrict__ Weff) {     // tiled bf16, see above
  const int e  = blockIdx.x;
  const int o0 = blockIdx.y * 32;
  const int c0 = blockIdx.z * 32;
  const int tid = threadIdx.x;
  const int ol = tid >> 3;           // 0..31
  const int cq = (tid & 7) * 4;      // 0..28

  __shared__ __align__(16) float sA[32 * 129];       // Wch gate part [o][k]
  __shared__ __align__(16) float sB[32 * 32 * 12];   // Ws chunk [k][c][12]

#pragma unroll
  for (int it = 0; it < 4; ++it) {
    int i4 = tid + it * 256;         // 0..1023
    int o  = i4 >> 5;                // 0..31
    int kk = (i4 & 31) * 4;          // 0..124
    float4 v = *(const float4*)(Wch + (size_t)(e * C_ + o0 + o) * 256 + 128 + kk);
    sA[o * 129 + kk + 0] = v.x;
    sA[o * 129 + kk + 1] = v.y;
    sA[o * 129 + kk + 2] = v.z;
    sA[o * 129 + kk + 3] = v.w;
  }

  float acc[9][4];
#pragma unroll
  for (int j = 0; j < 9; ++j)
#pragma unroll
    for (int c2 = 0; c2 < 4; ++c2) acc[j][c2] = 0.f;

  for (int k0 = 0; k0 < 128; k0 += 32) {
    __syncthreads();
    {  // stage sB: 32 k-rows, each 288 contiguous floats (32c x 9j), repack [k][c][12]
      int k = tid >> 3, seg = tid & 7;
      const float* src = Ws + ((size_t)(e * KN_ + k0 + k) * C_ + c0) * 9 + seg * 36;
      float vb[36];
#pragma unroll
      for (int q = 0; q < 9; ++q) {
        float4 v = *(const float4*)(src + q * 4);
        vb[q * 4 + 0] = v.x; vb[q * 4 + 1] = v.y;
        vb[q * 4 + 2] = v.z; vb[q * 4 + 3] = v.w;
      }
      int c = seg * 4, j = 0;   // seg*36 = (seg*4)*9 exactly
#pragma unroll
      for (int m = 0; m < 36; ++m) {
        sB[(k * 32 + c) * 12 + j] = vb[m];
        if (++j == 9) { j = 0; ++c; }
      }
    }
    __syncthreads();
    for (int k = 0; k < 32; ++k) {
      float a = sA[ol * 129 + k0 + k];
#pragma unroll
      for (int c2 = 0; c2 < 4; ++c2) {
        const float* bp = &sB[(k * 32 + cq + c2) * 12];
#pragma unroll
        for (int j = 0; j < 9; ++j) acc[j][c2] += a * bp[j];
      }
    }
  }

  const int o = o0 + ol;
#pragma unroll
  for (int c2 = 0; c2 < 4; ++c2)
    acc[4][c2] += Wch[(size_t)(e * C_ + o) * 256 + c0 + cq + c2];

  const int nt   = (o0 >> 4) + (ol >> 4);
  const int lane = ((cq >> 3) << 4) | (ol & 15);
#pragma unroll
  for (int j = 0; j < 9; ++j) {
    uint lo = (uint)f2bf(acc[j][0]) | ((uint)f2bf(acc[j][1]) << 16);
    uint hi = (uint)f2bf(acc[j][2]) | ((uint)f2bf(acc[j][3]) << 16);
    size_t base = ((((size_t)(e * 9 + j) * 8 + nt) * 4 + blockIdx.z) * 64 + lane) * 8
                  + (cq & 4);
    *(uint2*)(Weff + base) = make_uint2(lo, hi);
  }
}

// ---------------------------------------------------------------------------
// Kernel 2: implicit-GEMM MFMA conv, double-buffered global_load_lds pipeline.
// Per cc step: issue 30 x global_load_lds dwordx4 (1024 B each) into the
// other buffer, s_waitcnt vmcnt(30) (counted - previous batch landed, new
// batch stays in flight), raw s_barrier, compute 252 MFMAs. No vmcnt(0)
// drain in the main loop (T3/T4). B fragments direct from L2-resident Weff.
// LDS 2 x 30720 B -> 2 blocks/CU; launch_bounds(256,2) for VGPR headroom.
// ---------------------------------------------------------------------------
#define OSTR 228   // f32 epilogue o-stride (224 + 4 pad)

#define BAR() do { asm volatile("" ::: "memory"); \
                   __builtin_amdgcn_s_barrier();  \
                   asm volatile("" ::: "memory"); } while (0)

__global__ __launch_bounds__(256, 2) void conv_mfma_kernel(
    const ushort* __restrict__ xh,   // padded cc-plane layout, see prep
    const int* __restrict__ gate,    // [B][KSEL]
    const ushort* __restrict__ Weff, // fragment-tiled bf16
    float* __restrict__ out) {       // [B][KSEL][C][H][W] fp32
  // --- swizzled block mapping: XCD = P%8 gets b in [4*xcd, 4*xcd+4) ---
  const int P   = blockIdx.x;        // 0..895
  const int xcd = P & 7;
  const int s   = P >> 3;            // 0..111
  const int bl  = s / 28;
  const int r1  = s - bl * 28;
  const int g   = r1 / 14;
  const int ht  = r1 - g * 14;       // 0..13
  const int b   = xcd * 4 + bl;
  const int bg  = b * 2 + g;
  const int h0  = ht * 4;
  const int e   = gate[bg];

  const int tid = threadIdx.x;
  const int wv = tid >> 6, lane = tid & 63;
  const int l15 = lane & 15, kq = lane >> 4;
  const int mh = wv >> 1, nh = wv & 1;

  __shared__ __align__(128) char smem[2 * REG_B];   // 61440 B
  ushort* bufA = (ushort*)smem;
  ushort* bufB = (ushort*)(smem + REG_B);

  f32x4 acc[7][4];
#pragma unroll
  for (int t = 0; t < 7; ++t)
#pragma unroll
    for (int i = 0; i < 4; ++i) acc[t][i] = (f32x4){0.f, 0.f, 0.f, 0.f};

  int addr0[7];
#pragma unroll
  for (int t = 0; t < 7; ++t) {
    int p = mh * 112 + t * 16 + l15;   // 0..223
    int r = p / 56;
    int w = p - r * 56;
    addr0[t] = (r * 64 + w) * CELL_US + kq * 8;   // ushort index
  }

  // stage: 6 rows x 5120 B = 30 x 1024 B DMA chunks, waves round-robin
  const char* xbase = (const char*)xh;
#define STAGE(cc, dst) do {                                                   \
    const char* srp = xbase + ((size_t)((b * 4 + (cc)) * 58 + h0)) * ROW_B    \
                            + lane * 16;                                      \
    char* drp = (char*)(dst);                                                 \
    _Pragma("unroll")                                                         \
    for (int it_ = 0; it_ < 8; ++it_) {                                       \
      int n_ = wv + it_ * 4;                                                  \
      if (n_ < 30)                                                            \
        __builtin_amdgcn_global_load_lds(                                     \
            (const __attribute__((address_space(1))) unsigned int*)(srp + n_ * 1024), \
            (__attribute__((address_space(3))) unsigned int*)(drp + n_ * 1024),       \
            16, 0, 0);                                                        \
    }                                                                         \
  } while (0)

  const ushort* wlane = Weff + (size_t)e * (9 * 8 * 4 * 64 * 8)
                             + (size_t)(nh * 4) * (4 * 64 * 8)
                             + (size_t)lane * 8;

#define COMPUTE(sXb, cc) do {                                                 \
    _Pragma("unroll")                                                         \
    for (int dy = 0; dy < 3; ++dy) {                                          \
      _Pragma("unroll")                                                       \
      for (int dx = 0; dx < 3; ++dx) {                                        \
        const int j_ = dy * 3 + dx;                                           \
        short8 bfr[4];                                                        \
        _Pragma("unroll")                                                     \
        for (int i = 0; i < 4; ++i)                                           \
          bfr[i] = *(const short8*)(wlane + (size_t)j_ * (8 * 4 * 64 * 8)     \
                                          + (size_t)i * (4 * 64 * 8)          \
                                          + (size_t)(cc) * (64 * 8));         \
        const int ao = (dy * 64 + dx) * CELL_US;                              \
        _Pragma("unroll")                                                     \
        for (int t = 0; t < 7; ++t) {                                         \
          short8 a = *(const short8*)&(sXb)[addr0[t] + ao];                   \
          _Pragma("unroll")                                                   \
          for (int i = 0; i < 4; ++i)                                         \
            acc[t][i] = __builtin_amdgcn_mfma_f32_16x16x32_bf16(              \
                a, bfr[i], acc[t][i], 0, 0, 0);                               \
        }                                                                     \
      }                                                                       \
    }                                                                         \
  } while (0)

  STAGE(0, bufA);
  STAGE(1, bufB);
  asm volatile("s_waitcnt vmcnt(30)" ::: "memory");   // batch0 landed
  BAR();
  COMPUTE(bufA, 0);
  BAR();
  STAGE(2, bufA);
  asm volatile("s_waitcnt vmcnt(30)" ::: "memory");   // batch1 landed
  BAR();
  COMPUTE(bufB, 1);
  BAR();
  STAGE(3, bufB);
  asm volatile("s_waitcnt vmcnt(30)" ::: "memory");   // batch2 landed
  BAR();
  COMPUTE(bufA, 2);
  BAR();
  asm volatile("s_waitcnt vmcnt(0)" ::: "memory");    // batch3 landed
  BAR();
  COMPUTE(bufB, 3);

  // -------- LDS-transposed epilogue (sO = bufA; last compute read bufB) ----
  float* sO = (float*)bufA;
  for (int gq = 0; gq < 4; ++gq) {
    if (nh == (gq >> 1)) {
      const int gg = gq & 1;
#pragma unroll
      for (int ii = 0; ii < 2; ++ii) {
        const int i = gg * 2 + ii;
#pragma unroll
        for (int t = 0; t < 7; ++t) {
          int p0 = mh * 112 + t * 16 + kq * 4;
          int r  = p0 / 56;
          int w0 = p0 - r * 56;
          *(float4*)&sO[(ii * 16 + l15) * OSTR + r * 56 + w0] =
              make_float4(acc[t][i][0], acc[t][i][1], acc[t][i][2], acc[t][i][3]);
        }
      }
    }
    __syncthreads();   // staged data visible
    {
      float* ob = out + ((size_t)bg * C_ + 32 * gq) * (H_ * W_) + (size_t)h0 * W_;
#pragma unroll
      for (int k = 0; k < 7; ++k) {
        int idx = k * 256 + tid;        // 0..1791
        int ol  = idx / 56;
        int pos = idx - ol * 56;
        float4 v = *(const float4*)&sO[ol * OSTR + pos * 4];
        *(float4*)(ob + (size_t)ol * (H_ * W_) + pos * 4) = v;
      }
    }
    __syncthreads();   // write-out reads done before next group staging
  }
}

extern "C" void kernel_launch(void* const* d_in, const int* in_sizes, int n_in,
                              void* d_out, int out_size, void* d_ws, size_t ws_size,
                              hipStream_t stream) {
  const float* x    = (const float*)d_in[0];   // [32,128,56,56]
  const int*   gate = (const int*)d_in[1];     // [32,2]
  const float* Ws   = (const float*)d_in[2];   // [8,128,128,3,3]
  const float* Wch  = (const float*)d_in[3];   // [8,128,256,1,1]
  float* out = (float*)d_out;                  // [32,2,128,56,56]

  ushort* xh   = (ushort*)d_ws;                       // 32*4*58*2560 us = 38.0 MB
  ushort* Weff = xh + (size_t)32 * 4 * 58 * ROW_US;   // [8][9][8][4][64][8] bf16 = 2.36 MB

  dim3 g0(58, 32);
  prep_x_kernel<<<g0, 256, 0, stream>>>(x, xh);

  dim3 g1(8, 4, 4);
  fuse_weights_kernel<<<g1, 256, 0, stream>>>(Ws, Wch, Weff);

  dim3 g2(896);
  conv_mfma_kernel<<<g2, 256, 0, stream>>>(xh, gate, Weff, out);
}